// Round 2
// baseline (413.418 us; speedup 1.0000x reference)
//
#include <hip/hip_runtime.h>
#include <hip/hip_bf16.h>

// SoftmaxSetAttention: out = softmax(Q K^T / sqrt(D) + log(mult)) V
// B=2 H=16 LQ=LK=2048 D=128, fp32 in/out, bf16 MFMA compute (2% absmax budget).
constexpr int B_  = 2;
constexpr int H_  = 16;
constexpr int LQ_ = 2048;
constexpr int LK_ = 2048;
constexpr int D_  = 128;

constexpr int BM = 128;  // q rows per block (4 waves x 32)
constexpr int BN = 64;   // keys per K-iteration

// log2(e) / sqrt(128): folded into Q at bf16-convert time -> pure exp2 softmax
constexpr float SCALE_LOG2E = 0.12751649734586414f;

typedef short s16x4 __attribute__((ext_vector_type(4)));
typedef short s16x8 __attribute__((ext_vector_type(8)));
typedef float f32x4 __attribute__((ext_vector_type(4)));

constexpr int PS = 68;  // P scratch row stride (64 keys + pad)

static __device__ __forceinline__ short f2bf(float x) {
  __hip_bfloat16 h = __float2bfloat16(x);
  return *reinterpret_cast<short*>(&h);
}

static __device__ __forceinline__ s16x8 comb8(s16x4 lo, s16x4 hi) {
  return __builtin_shufflevector(lo, hi, 0, 1, 2, 3, 4, 5, 6, 7);
}

__global__ __launch_bounds__(256, 2)
void attn_fwd(const float* __restrict__ qg, const float* __restrict__ kg,
              const float* __restrict__ vg, const int* __restrict__ multg,
              float* __restrict__ outg) {
  // K: 64 keys x 128 d, stride 128, 16B blocks XOR-swizzled by (row&15)
  __shared__ alignas(16) short Ksh[64 * 128];    // 16384 B
  // V^T: 128 d x 64 keys, stride 64, 16B blocks XOR-swizzled by ((d>>1)&7)
  __shared__ alignas(16) short Vsh[128 * 64];    // 16384 B
  __shared__ alignas(16) short Psh[4][32 * PS];  // 17408 B (per-wave P scratch)
  __shared__ float biasSh[LK_];                  //  8192 B  -> total 58368 B

  const int tid  = threadIdx.x;
  const int w    = tid >> 6;        // wave 0..3
  const int lane = tid & 63;
  const int c    = lane & 15;       // MFMA m/n index
  const int qd   = lane >> 4;       // quad 0..3

  const int qb = blockIdx.x;        // 0..15
  const int bh = blockIdx.y;        // 0..31
  const int b  = bh >> 4;

  const float* qptr = qg + (size_t)bh * LQ_ * D_;
  const float* kptr = kg + (size_t)bh * LK_ * D_;
  const float* vptr = vg + (size_t)bh * LK_ * D_;
  float*       optr = outg + (size_t)bh * LQ_ * D_;
  const int*   mptr = multg + b * LK_;

  // ---- bias = log2(multiplicity) into LDS (once) ----
  for (int i = tid; i < LK_; i += 256)
    biasSh[i] = log2f((float)mptr[i]);

  // ---- Q fragments (A-layout, scale*log2e folded in), kept in registers ----
  const int q0 = qb * BM + w * 32;
  s16x8 qf[2][4];
#pragma unroll
  for (int qs = 0; qs < 2; ++qs) {
    const float* qrow = qptr + (size_t)(q0 + qs * 16 + c) * D_ + qd * 8;
#pragma unroll
    for (int kf = 0; kf < 4; ++kf) {
      float4 a = *(const float4*)(qrow + kf * 32);
      float4 bq = *(const float4*)(qrow + kf * 32 + 4);
      s16x4 lo, hi;
      lo[0] = f2bf(a.x * SCALE_LOG2E);  lo[1] = f2bf(a.y * SCALE_LOG2E);
      lo[2] = f2bf(a.z * SCALE_LOG2E);  lo[3] = f2bf(a.w * SCALE_LOG2E);
      hi[0] = f2bf(bq.x * SCALE_LOG2E); hi[1] = f2bf(bq.y * SCALE_LOG2E);
      hi[2] = f2bf(bq.z * SCALE_LOG2E); hi[3] = f2bf(bq.w * SCALE_LOG2E);
      qf[qs][kf] = comb8(lo, hi);
    }
  }

  // ---- accumulators / online-softmax state ----
  f32x4 o[2][8];
  float m_r[2][4], l_r[2][4];
#pragma unroll
  for (int qs = 0; qs < 2; ++qs) {
#pragma unroll
    for (int dt = 0; dt < 8; ++dt) o[qs][dt] = (f32x4){0.f, 0.f, 0.f, 0.f};
#pragma unroll
    for (int r = 0; r < 4; ++r) { m_r[qs][r] = -INFINITY; l_r[qs][r] = 0.f; }
  }

  const int u = lane;  // d-pair index for V staging

  for (int kt = 0; kt < LK_ / BN; ++kt) {
    const int k0 = kt * BN;
    __syncthreads();  // previous iteration's frag reads done (and biasSh ready)

    // ---- stage K tile (64 keys x 128 d) -> bf16 LDS, swizzled ----
#pragma unroll
    for (int i = 0; i < 8; ++i) {
      int f4  = tid + i * 256;       // 0..2047 float4s
      int row = f4 >> 5;             // key 0..63
      int d0  = (f4 & 31) * 4;       // 0..124
      float4 a = *(const float4*)(kptr + (size_t)(k0 + row) * D_ + d0);
      s16x4 t;
      t[0] = f2bf(a.x); t[1] = f2bf(a.y); t[2] = f2bf(a.z); t[3] = f2bf(a.w);
      int pos = (d0 >> 3) ^ (row & 15);           // 16B-block swizzle
      *(s16x4*)&Ksh[row * 128 + pos * 8 + (d0 & 4)] = t;
    }

    // ---- stage V tile transposed (d-major), swizzled 8-key blocks ----
#pragma unroll
    for (int r = 0; r < 2; ++r) {
      int kgrp = w + r * 4;          // 8-key group 0..7
      float2 f2v[8];
      const float* vrow = vptr + (size_t)(k0 + kgrp * 8) * D_ + 2 * u;
#pragma unroll
      for (int j = 0; j < 8; ++j) f2v[j] = *(const float2*)(vrow + (size_t)j * D_);
#pragma unroll
      for (int half = 0; half < 2; ++half) {
        int d = 2 * u + half;
        s16x8 t;
#pragma unroll
        for (int j = 0; j < 8; ++j)
          t[j] = f2bf(half ? f2v[j].y : f2v[j].x);
        int pos = kgrp ^ (u & 7);    // == kgrp ^ ((d>>1)&7)
        *(s16x8*)&Vsh[d * 64 + pos * 8] = t;
      }
    }
    __syncthreads();

    // ---- S = Q K^T (C-layout: row=qd*4+reg, col=c) ----
    f32x4 S[2][4];
#pragma unroll
    for (int qs = 0; qs < 2; ++qs)
#pragma unroll
      for (int ct = 0; ct < 4; ++ct) S[qs][ct] = (f32x4){0.f, 0.f, 0.f, 0.f};

#pragma unroll
    for (int ct = 0; ct < 4; ++ct) {
      const int krow = ct * 16 + c;
      const short* kb = &Ksh[krow * 128];
      s16x8 kfr[4];
#pragma unroll
      for (int kf = 0; kf < 4; ++kf)
        kfr[kf] = *(const s16x8*)&kb[((kf * 4 + qd) ^ c) * 8];
#pragma unroll
      for (int qs = 0; qs < 2; ++qs)
#pragma unroll
        for (int kf = 0; kf < 4; ++kf)
          S[qs][ct] = __builtin_amdgcn_mfma_f32_16x16x32_bf16(
              qf[qs][kf], kfr[kf], S[qs][ct], 0, 0, 0);
    }

    // ---- add bias, online softmax, write P to per-wave LDS scratch ----
    float bv[4];
#pragma unroll
    for (int ct = 0; ct < 4; ++ct) bv[ct] = biasSh[k0 + ct * 16 + c];

#pragma unroll
    for (int qs = 0; qs < 2; ++qs) {
      float mx[4];
#pragma unroll
      for (int reg = 0; reg < 4; ++reg) {
        float a0 = fmaxf(S[qs][0][reg] + bv[0], S[qs][1][reg] + bv[1]);
        float a1 = fmaxf(S[qs][2][reg] + bv[2], S[qs][3][reg] + bv[3]);
        mx[reg] = fmaxf(a0, a1);
      }
#pragma unroll
      for (int mask = 1; mask <= 8; mask <<= 1)
#pragma unroll
        for (int reg = 0; reg < 4; ++reg)
          mx[reg] = fmaxf(mx[reg], __shfl_xor(mx[reg], mask, 64));

      float al[4];
#pragma unroll
      for (int reg = 0; reg < 4; ++reg) {
        float mn = fmaxf(m_r[qs][reg], mx[reg]);
        al[reg] = exp2f(m_r[qs][reg] - mn);
        m_r[qs][reg] = mn;
      }
      float rs[4] = {0.f, 0.f, 0.f, 0.f};
#pragma unroll
      for (int ct = 0; ct < 4; ++ct)
#pragma unroll
        for (int reg = 0; reg < 4; ++reg) {
          float p = exp2f(S[qs][ct][reg] + bv[ct] - m_r[qs][reg]);
          S[qs][ct][reg] = p;
          rs[reg] += p;
        }
#pragma unroll
      for (int mask = 1; mask <= 8; mask <<= 1)
#pragma unroll
        for (int reg = 0; reg < 4; ++reg)
          rs[reg] += __shfl_xor(rs[reg], mask, 64);
#pragma unroll
      for (int reg = 0; reg < 4; ++reg)
        l_r[qs][reg] = l_r[qs][reg] * al[reg] + rs[reg];
#pragma unroll
      for (int dt = 0; dt < 8; ++dt)
#pragma unroll
        for (int reg = 0; reg < 4; ++reg) o[qs][dt][reg] *= al[reg];

      // C-layout -> LDS (row = q within 32, col = key within 64)
#pragma unroll
      for (int ct = 0; ct < 4; ++ct)
#pragma unroll
        for (int reg = 0; reg < 4; ++reg)
          Psh[w][(qs * 16 + qd * 4 + reg) * PS + ct * 16 + c] =
              f2bf(S[qs][ct][reg]);
    }

    // ---- O += P V  (P re-read in A-layout, V^T b-frags via swizzle) ----
    s16x8 pf[2][2];
#pragma unroll
    for (int qs = 0; qs < 2; ++qs)
#pragma unroll
      for (int kf = 0; kf < 2; ++kf) {
        const short* pb = &Psh[w][(qs * 16 + c) * PS + kf * 32 + qd * 8];
        pf[qs][kf] = comb8(*(const s16x4*)pb, *(const s16x4*)(pb + 4));
      }
#pragma unroll
    for (int dt = 0; dt < 8; ++dt) {
      int d = dt * 16 + c;
      const short* vb = &Vsh[d * 64];
      s16x8 vf[2];
#pragma unroll
      for (int kf = 0; kf < 2; ++kf)
        vf[kf] = *(const s16x8*)&vb[((kf * 4 + qd) ^ ((d >> 1) & 7)) * 8];
#pragma unroll
      for (int qs = 0; qs < 2; ++qs)
#pragma unroll
        for (int kf = 0; kf < 2; ++kf)
          o[qs][dt] = __builtin_amdgcn_mfma_f32_16x16x32_bf16(
              pf[qs][kf], vf[kf], o[qs][dt], 0, 0, 0);
    }
  }

  // ---- epilogue: normalize and store fp32 ----
#pragma unroll
  for (int qs = 0; qs < 2; ++qs)
#pragma unroll
    for (int reg = 0; reg < 4; ++reg) {
      float inv = 1.0f / l_r[qs][reg];
      int row = q0 + qs * 16 + qd * 4 + reg;
      float* orow = optr + (size_t)row * D_ + c;
#pragma unroll
      for (int dt = 0; dt < 8; ++dt) orow[dt * 16] = o[qs][dt][reg] * inv;
    }
}

extern "C" void kernel_launch(void* const* d_in, const int* in_sizes, int n_in,
                              void* d_out, int out_size, void* d_ws, size_t ws_size,
                              hipStream_t stream) {
  const float* q = (const float*)d_in[0];
  const float* k = (const float*)d_in[1];
  const float* v = (const float*)d_in[2];
  const int* mult = (const int*)d_in[3];
  float* out = (float*)d_out;

  dim3 grid(LQ_ / BM, B_ * H_);
  dim3 block(256);
  attn_fwd<<<grid, block, 0, stream>>>(q, k, v, mult, out);
}